// Round 2
// baseline (250.736 us; speedup 1.0000x reference)
//
#include <hip/hip_runtime.h>

#define DIN   2048
#define DOUT  2048
#define NP    16
#define TPW   8    // tokens per wave; 1 wave per block

// ws layout (byte offsets)
#define HDR_OFF   0                      // 2 floats: w1, w2
#define WK4_OFF   256                    // 8192 u32 (32 KB) ternary Wk
#define WV4_OFF   (WK4_OFF + 32768)      // 2048 uint4 (32 KB) ternary Wv rows

static __device__ __forceinline__ int dot4(unsigned a, unsigned b, int c) {
#if defined(__has_builtin) && __has_builtin(__builtin_amdgcn_sdot4)
  return __builtin_amdgcn_sdot4((int)a, (int)b, c, false);
#else
  c += (int)(signed char)(a & 0xffu)        * (int)(signed char)(b & 0xffu);
  c += (int)(signed char)((a >> 8) & 0xffu) * (int)(signed char)((b >> 8) & 0xffu);
  c += (int)(signed char)((a >> 16) & 0xffu)* (int)(signed char)((b >> 16) & 0xffu);
  c += (int)(signed char)(a >> 24)          * (int)(signed char)(b >> 24);
  return c;
#endif
}

// fma-magic int8 quantize: low byte of (f*xs + 1.5*2^23) = round-to-even(f*xs)
static __device__ __forceinline__ unsigned qmagic(float f, float xs) {
  return __float_as_uint(fmaf(f, xs, 12582912.0f)) & 0xffu;
}

// reference-exact double-rounded quantize (epilogue 16-value re-quant)
static __device__ __forceinline__ unsigned q8(float f, float xs) {
  float t = f * xs;
  float r = rintf(t);
  r = fmaxf(-128.0f, fminf(127.0f, r));
  return ((unsigned)(int)r) & 0xffu;
}

// ---------------------------------------------------------------------------
// k_prep: fused reduce+pack, 40 blocks. Same op order as the original
// two-stage reduce (8 virtual partials, per-partial 256-tree, sequential sum)
// -> bitwise-identical scale. Blocks 0-31 pack Wk slices, 32-39 pack Wv rows.
// ---------------------------------------------------------------------------
__global__ __launch_bounds__(256) void k_prep(
    const float* __restrict__ Wk, const float* __restrict__ Wv,
    float* __restrict__ hdr, unsigned* __restrict__ wk4, unsigned* __restrict__ wv4)
{
  __shared__ float red[8][256];
  const int tid = threadIdx.x, b = blockIdx.x;
  const int isV = (b >= 32);
  const float4* W = (const float4*)(isV ? Wv : Wk);

  float4 own = make_float4(0.f, 0.f, 0.f, 0.f);
#pragma unroll
  for (int lb = 0; lb < 8; ++lb) {
    float s = 0.f;
#pragma unroll
    for (int i = 0; i < 4; ++i) {
      float4 v = W[lb * 1024 + i * 256 + tid];
      if (!isV && (lb * 4 + i) == b) own = v;   // capture own pack slice
      s += fabsf(v.x) + fabsf(v.y) + fabsf(v.z) + fabsf(v.w);
    }
    red[lb][tid] = s;
  }
  __syncthreads();
#pragma unroll 1
  for (int o = 128; o > 0; o >>= 1) {
    if (tid < o) {
#pragma unroll
      for (int lb = 0; lb < 8; ++lb) red[lb][tid] += red[lb][tid + o];
    }
    __syncthreads();
  }
  float sum = 0.f;
#pragma unroll
  for (int lb = 0; lb < 8; ++lb) sum += red[lb][0];
  const float sc = fmaxf(sum * (1.0f / 32768.0f), 1e-5f);
  if (tid == 0 && (b == 0 || b == 32)) hdr[isV] = sc;

  if (!isV) {
    const int c = b * 256 + tid;          // [0, 8192)
    unsigned pk = 0; const float* wp = &own.x;
#pragma unroll
    for (int j = 0; j < 4; ++j) {
      float r = rintf(wp[j] / sc);
      r = fmaxf(-1.0f, fminf(1.0f, r));
      pk |= (((unsigned)(int)r) & 0xffu) << (8 * j);
    }
    wk4[c] = pk;
  } else {
    const int o = (b - 32) * 256 + tid;   // row [0, 2048)
    unsigned u[4];
#pragma unroll
    for (int cc = 0; cc < 4; ++cc) {
      float4 w = ((const float4*)Wv)[o * 4 + cc];   // L2-hot re-read
      const float* wp = &w.x;
      unsigned pk = 0;
#pragma unroll
      for (int r = 0; r < 4; ++r) {
        float q = rintf(wp[r] / sc);
        q = fmaxf(-1.0f, fminf(1.0f, q));
        pk |= (((unsigned)(int)q) & 0xffu) << (8 * r);
      }
      u[cc] = pk;
    }
    ((uint4*)wv4)[o] = make_uint4(u[0], u[1], u[2], u[3]);
  }
}

// ---------------------------------------------------------------------------
// k_main: fused kA+kB, ONE wave per block, 2048 blocks (= exactly 2 waves/SIMD
// chip-wide). amdgpu_waves_per_eu(2,2) pins the backend's occupancy target to
// what the grid actually delivers -> VGPR budget 256 -> the ~235-reg working
// set (tab[128] Wk table + a[2][8] x double-buffer + acc[16] + qp[8]) stays
// register-resident. Round-1's launch_bounds(128,2) let the compiler chase
// 4 waves/EU (unreachable at this grid) and spill ~100 regs into the
// per-token loop -> 24k cycles/token. This build must show VGPR ~230-256.
// ---------------------------------------------------------------------------
__global__ __attribute__((amdgpu_waves_per_eu(2, 2))) __launch_bounds__(64)
void k_main(
    const float* __restrict__ x, const float* __restrict__ hdr,
    const unsigned* __restrict__ wk4, const unsigned* __restrict__ wv4,
    float* __restrict__ out)
{
  const int l  = threadIdx.x;
  const long t0 = (long)blockIdx.x * TPW;

  __shared__ uint4 qls[TPW];
  __shared__ float sls[TPW];

  const float w1 = hdr[0], w2 = hdr[1];
  const float4* xf = (const float4*)x;

  // ---- phase A: Wk table register-resident ----
  unsigned tab[128];
#pragma unroll
  for (int p = 0; p < 16; ++p)
#pragma unroll
    for (int c = 0; c < 8; ++c) tab[p * 8 + c] = wk4[p * 512 + c * 64 + l];

  float4 a[2][8];
#pragma unroll
  for (int c = 0; c < 8; ++c) a[0][c] = xf[t0 * 512 + c * 64 + l];

#pragma unroll 1
  for (int g = 0; g < TPW / 4; ++g) {
    int   sv[4];
    float s1[4];
#pragma unroll
    for (int ii = 0; ii < 4; ++ii) {                     // unrolled: static idx
      const long tok = t0 + g * 4 + ii;

      // absmax over this token (full wave)
      float mx = 0.0f;
#pragma unroll
      for (int c = 0; c < 8; ++c) {
        float4 v = a[ii & 1][c];
        mx = fmaxf(mx, fabsf(v.x)); mx = fmaxf(mx, fabsf(v.y));
        mx = fmaxf(mx, fabsf(v.z)); mx = fmaxf(mx, fabsf(v.w));
      }
#pragma unroll
      for (int d = 1; d < 64; d <<= 1) mx = fmaxf(mx, __shfl_xor(mx, d, 64));
      const float mcl = fmaxf(mx, 1e-5f);
      const float xs  = 127.0f / mcl;
      s1[ii] = w1 / xs;

      // quantize (|f*xs| <= 127 exactly, no clamp needed)
      unsigned qp[8];
#pragma unroll
      for (int c = 0; c < 8; ++c) {
        float4 v = a[ii & 1][c];
        qp[c] = qmagic(v.x, xs) | (qmagic(v.y, xs) << 8)
              | (qmagic(v.z, xs) << 16) | (qmagic(v.w, xs) << 24);
      }

      // prefetch next token into the other buffer (hides HBM latency
      // under the dot + reduce-scatter work below)
      if (g * 4 + ii < TPW - 1) {
#pragma unroll
        for (int c = 0; c < 8; ++c)
          a[(ii + 1) & 1][c] = xf[(tok + 1) * 512 + c * 64 + l];
      }

      // 16 integer dot rows (partial over this lane's 32 k's)
      int acc[16];
#pragma unroll
      for (int p = 0; p < 16; ++p) {
        int d = 0;
#pragma unroll
        for (int c = 0; c < 8; ++c) d = dot4(qp[c], tab[p * 8 + c], d);
        acc[p] = d;
      }

      // recursive-halving reduce-scatter, identity perm (p = l&15)
#pragma unroll
      for (int b = 0; b < 4; ++b) {
        const int lb = (l >> b) & 1;
#pragma unroll
        for (int j = 0; j < 8; ++j) {
          if (j < (8 >> b)) {
            int keep = lb ? acc[2 * j + 1] : acc[2 * j];
            int send = lb ? acc[2 * j]     : acc[2 * j + 1];
            acc[j] = keep + __shfl_xor(send, 1 << b, 64);
          }
        }
      }
      sv[ii] = acc[0];
    }

    // ---- group epilogue: route 4 token slots over lane bits 4/5 ----
    const int lb4 = (l >> 4) & 1, lb5 = (l >> 5) & 1;
    int r0 = (lb4 ? sv[1] : sv[0]) + __shfl_xor(lb4 ? sv[0] : sv[1], 16, 64);
    int r1 = (lb4 ? sv[3] : sv[2]) + __shfl_xor(lb4 ? sv[2] : sv[3], 16, 64);
    int rr = (lb5 ? r1 : r0) + __shfl_xor(lb5 ? r0 : r1, 32, 64);
    float s1a = lb4 ? s1[1] : s1[0];
    float s1b = lb4 ? s1[3] : s1[2];
    const float s1sel = lb5 ? s1b : s1a;

    const float fa = (float)rr * s1sel;
    const float gv = 0.5f * fa * (1.0f + erff(fa * 0.70710678118654752f));
    float ss = gv * gv;
    ss += __shfl_xor(ss, 1, 64); ss += __shfl_xor(ss, 2, 64);
    ss += __shfl_xor(ss, 4, 64); ss += __shfl_xor(ss, 8, 64);
    const float rn = fmaxf(sqrtf(ss), 1e-12f);
    const float gn = gv * (4.0f / rn);
    float am = fabsf(gn);
    {
      float o;
      o = __shfl_xor(am, 1, 64); am = fmaxf(am, o);
      o = __shfl_xor(am, 2, 64); am = fmaxf(am, o);
      o = __shfl_xor(am, 4, 64); am = fmaxf(am, o);
      o = __shfl_xor(am, 8, 64); am = fmaxf(am, o);
    }
    const float mc2 = fmaxf(am, 1e-5f);
    const float xs2 = 127.0f / mc2;
    const float s2  = w2 / xs2;

    unsigned sh = q8(gn, xs2) << ((l & 3) * 8);
    sh |= (unsigned)__shfl_xor((int)sh, 1, 64);
    sh |= (unsigned)__shfl_xor((int)sh, 2, 64);
    const unsigned wa = (unsigned)__shfl_xor((int)sh, 4, 64);
    const unsigned wb = (unsigned)__shfl_xor((int)sh, 8, 64);
    const unsigned wc = (unsigned)__shfl_xor((int)sh, 12, 64);
    if ((l & 15) == 0) {
      qls[g * 4 + (l >> 4)] = make_uint4(sh, wa, wb, wc);
      sls[g * 4 + (l >> 4)] = s2;
    }
  }

  // ---- phase B: reload the SAME table array with Wv rows ----
#pragma unroll
  for (int m = 0; m < 8; ++m)
#pragma unroll
    for (int j = 0; j < 4; ++j) {
      uint4 t = ((const uint4*)wv4)[m * 256 + l * 4 + j];
      tab[(m * 4 + j) * 4 + 0] = t.x; tab[(m * 4 + j) * 4 + 1] = t.y;
      tab[(m * 4 + j) * 4 + 2] = t.z; tab[(m * 4 + j) * 4 + 3] = t.w;
    }

  // LDS write->read ordering (single wave: cheap)
  __syncthreads();

  for (int i = 0; i < TPW; ++i) {
    const long tok = t0 + i;
    const uint4 q  = qls[i];
    const float s2 = sls[i];
#pragma unroll
    for (int m = 0; m < 8; ++m) {
      float h[4];
#pragma unroll
      for (int j = 0; j < 4; ++j) {
        int d = dot4(q.x, tab[(m * 4 + j) * 4 + 0], 0);
        d = dot4(q.y, tab[(m * 4 + j) * 4 + 1], d);
        d = dot4(q.z, tab[(m * 4 + j) * 4 + 2], d);
        d = dot4(q.w, tab[(m * 4 + j) * 4 + 3], d);
        h[j] = (float)d * s2;
      }
      *(float4*)(out + (size_t)tok * 2048 + m * 256 + l * 4) =
          make_float4(h[0], h[1], h[2], h[3]);
    }
  }
}

extern "C" void kernel_launch(void* const* d_in, const int* in_sizes, int n_in,
                              void* d_out, int out_size, void* d_ws, size_t ws_size,
                              hipStream_t stream) {
  const float* x  = (const float*)d_in[0];
  const float* Wk = (const float*)d_in[1];
  const float* Wv = (const float*)d_in[2];

  const int tokens = in_sizes[0] / DIN;  // 16384

  char* ws = (char*)d_ws;
  float*    hdr = (float*)(ws + HDR_OFF);
  unsigned* wk4 = (unsigned*)(ws + WK4_OFF);
  unsigned* wv4 = (unsigned*)(ws + WV4_OFF);

  k_prep<<<40, 256, 0, stream>>>(Wk, Wv, hdr, wk4, wv4);
  k_main<<<tokens / TPW, 64, 0, stream>>>(x, hdr, wk4, wv4, (float*)d_out);
}

// Round 3
// 249.383 us; speedup vs baseline: 1.0054x; 1.0054x over previous
//
#include <hip/hip_runtime.h>

#define DIN   2048
#define DOUT  2048
#define NP    16
#define TPW   8    // tokens per wave
#define WPB   4    // waves per block (share LDS weight tables)

// ws layout (byte offsets)
#define HDR_OFF   0                      // 2 floats: w1, w2
#define WK4_OFF   256                    // 8192 u32 (32 KB) ternary Wk
#define WV4_OFF   (WK4_OFF + 32768)      // 2048 uint4 (32 KB) ternary Wv rows

static __device__ __forceinline__ int dot4(unsigned a, unsigned b, int c) {
#if defined(__has_builtin) && __has_builtin(__builtin_amdgcn_sdot4)
  return __builtin_amdgcn_sdot4((int)a, (int)b, c, false);
#else
  c += (int)(signed char)(a & 0xffu)        * (int)(signed char)(b & 0xffu);
  c += (int)(signed char)((a >> 8) & 0xffu) * (int)(signed char)((b >> 8) & 0xffu);
  c += (int)(signed char)((a >> 16) & 0xffu)* (int)(signed char)((b >> 16) & 0xffu);
  c += (int)(signed char)(a >> 24)          * (int)(signed char)(b >> 24);
  return c;
#endif
}

// fma-magic int8 quantize: low byte of (f*xs + 1.5*2^23) = round-to-even(f*xs)
static __device__ __forceinline__ unsigned qmagic(float f, float xs) {
  return __float_as_uint(fmaf(f, xs, 12582912.0f)) & 0xffu;
}

// reference-exact double-rounded quantize (epilogue 16-value re-quant)
static __device__ __forceinline__ unsigned q8(float f, float xs) {
  float t = f * xs;
  float r = rintf(t);
  r = fmaxf(-128.0f, fminf(127.0f, r));
  return ((unsigned)(int)r) & 0xffu;
}

// ---------------------------------------------------------------------------
// k_prep: fused reduce+pack, 40 blocks. Same op order as the original
// two-stage reduce (8 virtual partials, per-partial 256-tree, sequential sum)
// -> bitwise-identical scale. Blocks 0-31 pack Wk slices, 32-39 pack Wv rows.
// ---------------------------------------------------------------------------
__global__ __launch_bounds__(256) void k_prep(
    const float* __restrict__ Wk, const float* __restrict__ Wv,
    float* __restrict__ hdr, unsigned* __restrict__ wk4, unsigned* __restrict__ wv4)
{
  __shared__ float red[8][256];
  const int tid = threadIdx.x, b = blockIdx.x;
  const int isV = (b >= 32);
  const float4* W = (const float4*)(isV ? Wv : Wk);

  float4 own = make_float4(0.f, 0.f, 0.f, 0.f);
#pragma unroll
  for (int lb = 0; lb < 8; ++lb) {
    float s = 0.f;
#pragma unroll
    for (int i = 0; i < 4; ++i) {
      float4 v = W[lb * 1024 + i * 256 + tid];
      if (!isV && (lb * 4 + i) == b) own = v;   // capture own pack slice
      s += fabsf(v.x) + fabsf(v.y) + fabsf(v.z) + fabsf(v.w);
    }
    red[lb][tid] = s;
  }
  __syncthreads();
#pragma unroll 1
  for (int o = 128; o > 0; o >>= 1) {
    if (tid < o) {
#pragma unroll
      for (int lb = 0; lb < 8; ++lb) red[lb][tid] += red[lb][tid + o];
    }
    __syncthreads();
  }
  float sum = 0.f;
#pragma unroll
  for (int lb = 0; lb < 8; ++lb) sum += red[lb][0];
  const float sc = fmaxf(sum * (1.0f / 32768.0f), 1e-5f);
  if (tid == 0 && (b == 0 || b == 32)) hdr[isV] = sc;

  if (!isV) {
    const int c = b * 256 + tid;          // [0, 8192)
    unsigned pk = 0; const float* wp = &own.x;
#pragma unroll
    for (int j = 0; j < 4; ++j) {
      float r = rintf(wp[j] / sc);
      r = fmaxf(-1.0f, fminf(1.0f, r));
      pk |= (((unsigned)(int)r) & 0xffu) << (8 * j);
    }
    wk4[c] = pk;
  } else {
    const int o = (b - 32) * 256 + tid;   // row [0, 2048)
    unsigned u[4];
#pragma unroll
    for (int cc = 0; cc < 4; ++cc) {
      float4 w = ((const float4*)Wv)[o * 4 + cc];   // L2-hot re-read
      const float* wp = &w.x;
      unsigned pk = 0;
#pragma unroll
      for (int r = 0; r < 4; ++r) {
        float q = rintf(wp[r] / sc);
        q = fmaxf(-1.0f, fminf(1.0f, q));
        pk |= (((unsigned)(int)q) & 0xffu) << (8 * r);
      }
      u[cc] = pk;
    }
    ((uint4*)wv4)[o] = make_uint4(u[0], u[1], u[2], u[3]);
  }
}

// ---------------------------------------------------------------------------
// k_main: fused kA+kB. Block = 4 waves sharing LDS weight tables; each wave
// owns 8 tokens. Round-2 lesson: a 128-reg private weight table gets
// REMATERIALIZED by the backend (VGPR pinned at 124, zero scratch traffic,
// ~200-cyc re-load serialized per sdot4 -> 25k cyc/token). Here the tables
// live in LDS instead:
//   wkL: [p][c2][lane][c'] so phase A reads 2x ds_read_b128 per p
//        (contiguous 16 B per lane - conflict-free standard pattern)
//   wvL: [m*4+j][lane] uint4 so phase B reads 1x ds_read_b128 per (m,j),
//        amortized over all 8 tokens (32 reads total, token-independent)
// VGPR working set drops to ~115 (a[2][8] dbuf + qp[8] + acc[16] / h[8][4]);
// LDS 66 KB caps occupancy at 2 blocks/CU = 2 waves/SIMD = exactly the grid.
// Arithmetic order identical to the passing kernel -> bitwise-same output.
// ---------------------------------------------------------------------------
__global__ __launch_bounds__(256) void k_main(
    const float* __restrict__ x, const float* __restrict__ hdr,
    const unsigned* __restrict__ wk4, const unsigned* __restrict__ wv4,
    float* __restrict__ out)
{
  const int tid = threadIdx.x;
  const int l   = tid & 63;
  const int ws  = tid >> 6;
  const long t0 = ((long)blockIdx.x * WPB + ws) * TPW;

  __shared__ uint4 wkL[2048];        // 32 KB ternary Wk, b128-friendly layout
  __shared__ uint4 wvL[2048];        // 32 KB ternary Wv, b128-friendly layout
  __shared__ uint4 qls[WPB][TPW];    // per-wave q2 handoff
  __shared__ float sls[WPB][TPW];    // per-wave s2 handoff

  const float w1 = hdr[0], w2 = hdr[1];
  const float4* xf = (const float4*)x;

  // issue first-token x loads before the fills (overlap HBM latency)
  float4 a[2][8];
#pragma unroll
  for (int c = 0; c < 8; ++c) a[0][c] = xf[t0 * 512 + c * 64 + l];

  // ---- cooperative LDS fills (one-time; conflicts here are negligible) ----
  {
    unsigned* wkW = (unsigned*)wkL;
#pragma unroll
    for (int i = 0; i < 32; ++i) {
      const int g = i * 256 + tid;            // natural wk4 word index
      const unsigned v = wk4[g];
      const int p = g >> 9, rem = g & 511, c = rem >> 6, lg = rem & 63;
      wkW[p * 512 + (c >> 2) * 256 + lg * 4 + (c & 3)] = v;
    }
#pragma unroll
    for (int i = 0; i < 8; ++i) {
      const int o = i * 256 + tid;            // Wv row
      const uint4 v = ((const uint4*)wv4)[o];
      const int m = o >> 8, r = o & 255, lr = r >> 2, j = r & 3;
      wvL[(m * 4 + j) * 64 + lr] = v;
    }
  }
  __syncthreads();

  // ---- phase A ----
#pragma unroll 1
  for (int g = 0; g < TPW / 4; ++g) {
    int   sv[4];
    float s1[4];
#pragma unroll
    for (int ii = 0; ii < 4; ++ii) {                     // unrolled: static idx
      const long tok = t0 + g * 4 + ii;

      // absmax over this token (full wave)
      float mx = 0.0f;
#pragma unroll
      for (int c = 0; c < 8; ++c) {
        float4 v = a[ii & 1][c];
        mx = fmaxf(mx, fabsf(v.x)); mx = fmaxf(mx, fabsf(v.y));
        mx = fmaxf(mx, fabsf(v.z)); mx = fmaxf(mx, fabsf(v.w));
      }
#pragma unroll
      for (int d = 1; d < 64; d <<= 1) mx = fmaxf(mx, __shfl_xor(mx, d, 64));
      const float mcl = fmaxf(mx, 1e-5f);
      const float xs  = 127.0f / mcl;
      s1[ii] = w1 / xs;

      // quantize (|f*xs| <= 127 exactly, no clamp needed)
      unsigned qp[8];
#pragma unroll
      for (int c = 0; c < 8; ++c) {
        float4 v = a[ii & 1][c];
        qp[c] = qmagic(v.x, xs) | (qmagic(v.y, xs) << 8)
              | (qmagic(v.z, xs) << 16) | (qmagic(v.w, xs) << 24);
      }

      // prefetch next token into the other buffer
      if (g * 4 + ii < TPW - 1) {
#pragma unroll
        for (int c = 0; c < 8; ++c)
          a[(ii + 1) & 1][c] = xf[(tok + 1) * 512 + c * 64 + l];
      }

      // 16 integer dot rows from LDS (2x ds_read_b128 per p)
      int acc[16];
#pragma unroll
      for (int p = 0; p < 16; ++p) {
        const uint4 w0 = wkL[p * 128 + l];        // c = 0..3
        const uint4 w4 = wkL[p * 128 + 64 + l];   // c = 4..7
        int d = 0;
        d = dot4(qp[0], w0.x, d); d = dot4(qp[1], w0.y, d);
        d = dot4(qp[2], w0.z, d); d = dot4(qp[3], w0.w, d);
        d = dot4(qp[4], w4.x, d); d = dot4(qp[5], w4.y, d);
        d = dot4(qp[6], w4.z, d); d = dot4(qp[7], w4.w, d);
        acc[p] = d;
      }

      // recursive-halving reduce-scatter, identity perm (p = l&15)
#pragma unroll
      for (int b = 0; b < 4; ++b) {
        const int lb = (l >> b) & 1;
#pragma unroll
        for (int j = 0; j < 8; ++j) {
          if (j < (8 >> b)) {
            int keep = lb ? acc[2 * j + 1] : acc[2 * j];
            int send = lb ? acc[2 * j]     : acc[2 * j + 1];
            acc[j] = keep + __shfl_xor(send, 1 << b, 64);
          }
        }
      }
      sv[ii] = acc[0];
    }

    // ---- group epilogue: route 4 token slots over lane bits 4/5 ----
    const int lb4 = (l >> 4) & 1, lb5 = (l >> 5) & 1;
    int r0 = (lb4 ? sv[1] : sv[0]) + __shfl_xor(lb4 ? sv[0] : sv[1], 16, 64);
    int r1 = (lb4 ? sv[3] : sv[2]) + __shfl_xor(lb4 ? sv[2] : sv[3], 16, 64);
    int rr = (lb5 ? r1 : r0) + __shfl_xor(lb5 ? r0 : r1, 32, 64);
    float s1a = lb4 ? s1[1] : s1[0];
    float s1b = lb4 ? s1[3] : s1[2];
    const float s1sel = lb5 ? s1b : s1a;

    const float fa = (float)rr * s1sel;
    const float gv = 0.5f * fa * (1.0f + erff(fa * 0.70710678118654752f));
    float ss = gv * gv;
    ss += __shfl_xor(ss, 1, 64); ss += __shfl_xor(ss, 2, 64);
    ss += __shfl_xor(ss, 4, 64); ss += __shfl_xor(ss, 8, 64);
    const float rn = fmaxf(sqrtf(ss), 1e-12f);
    const float gn = gv * (4.0f / rn);
    float am = fabsf(gn);
    {
      float o;
      o = __shfl_xor(am, 1, 64); am = fmaxf(am, o);
      o = __shfl_xor(am, 2, 64); am = fmaxf(am, o);
      o = __shfl_xor(am, 4, 64); am = fmaxf(am, o);
      o = __shfl_xor(am, 8, 64); am = fmaxf(am, o);
    }
    const float mc2 = fmaxf(am, 1e-5f);
    const float xs2 = 127.0f / mc2;
    const float s2  = w2 / xs2;

    unsigned sh = q8(gn, xs2) << ((l & 3) * 8);
    sh |= (unsigned)__shfl_xor((int)sh, 1, 64);
    sh |= (unsigned)__shfl_xor((int)sh, 2, 64);
    const unsigned wa = (unsigned)__shfl_xor((int)sh, 4, 64);
    const unsigned wb = (unsigned)__shfl_xor((int)sh, 8, 64);
    const unsigned wc = (unsigned)__shfl_xor((int)sh, 12, 64);
    if ((l & 15) == 0) {
      qls[ws][g * 4 + (l >> 4)] = make_uint4(sh, wa, wb, wc);
      sls[ws][g * 4 + (l >> 4)] = s2;
    }
  }

  // ---- phase B: Wv fragments from LDS, amortized across all 8 tokens ----
  // (qls/sls are wave-private: same-wave ds_write -> ds_read is in-order)
  uint4 q[TPW]; float s2v[TPW];
#pragma unroll
  for (int i = 0; i < TPW; ++i) { q[i] = qls[ws][i]; s2v[i] = sls[ws][i]; }

#pragma unroll
  for (int m = 0; m < 8; ++m) {
    float h[TPW][4];
#pragma unroll
    for (int j = 0; j < 4; ++j) {
      const uint4 w = wvL[(m * 4 + j) * 64 + l];
#pragma unroll
      for (int t = 0; t < TPW; ++t) {
        int d = dot4(q[t].x, w.x, 0);
        d = dot4(q[t].y, w.y, d);
        d = dot4(q[t].z, w.z, d);
        d = dot4(q[t].w, w.w, d);
        h[t][j] = (float)d * s2v[t];
      }
    }
#pragma unroll
    for (int t = 0; t < TPW; ++t) {
      *(float4*)(out + (size_t)(t0 + t) * 2048 + m * 256 + l * 4) =
          make_float4(h[t][0], h[t][1], h[t][2], h[t][3]);
    }
  }
}

extern "C" void kernel_launch(void* const* d_in, const int* in_sizes, int n_in,
                              void* d_out, int out_size, void* d_ws, size_t ws_size,
                              hipStream_t stream) {
  const float* x  = (const float*)d_in[0];
  const float* Wk = (const float*)d_in[1];
  const float* Wv = (const float*)d_in[2];

  const int tokens = in_sizes[0] / DIN;  // 16384

  char* ws = (char*)d_ws;
  float*    hdr = (float*)(ws + HDR_OFF);
  unsigned* wk4 = (unsigned*)(ws + WK4_OFF);
  unsigned* wv4 = (unsigned*)(ws + WV4_OFF);

  k_prep<<<40, 256, 0, stream>>>(Wk, Wv, hdr, wk4, wv4);
  k_main<<<tokens / (TPW * WPB), 256, 0, stream>>>(x, hdr, wk4, wv4, (float*)d_out);
}